// Round 7
// baseline (212.523 us; speedup 1.0000x reference)
//
#include <hip/hip_runtime.h>
#include <stdint.h>

#define NTOK 16384
#define CDIM 1024
#define DHEAD 256

typedef short s16x8 __attribute__((ext_vector_type(8)));
typedef unsigned short u16x8 __attribute__((ext_vector_type(8)));
typedef _Float16 h16x8 __attribute__((ext_vector_type(8)));
typedef float f32x4 __attribute__((ext_vector_type(4)));

static __device__ __forceinline__ unsigned short f2bf(float f) {
    union { float f; unsigned u; } x; x.f = f;
    unsigned r = (x.u + 0x7fffu + ((x.u >> 16) & 1u)) >> 16;
    return (unsigned short)r;
}
static __device__ __forceinline__ unsigned short f2h(float f) {
    _Float16 h = (_Float16)f;
    return __builtin_bit_cast(unsigned short, h);
}
// Barrier ordering LDS only — global loads stay in flight across it (T4).
static __device__ __forceinline__ void lgkm_barrier() {
    asm volatile("s_waitcnt lgkmcnt(0)" ::: "memory");
    __builtin_amdgcn_s_barrier();
}

// ---------------------------------------------------------------------------
// Kernel 1: partial Gram G[de][e] over an n-chunk + per-channel sums.
// 512 thr / 8 waves, 1 block/CU. Staging via global_load_lds (zero staging
// VGPRs): stage s+1's 64 KB issued in bulk at the top of stage s, then
// counted s_waitcnt vmcnt(8) (stage-s data landed; s+1 stays in flight).
// LDS: raw f32 [2][32 rows][256 ch] for q and k (128 KB dynamic).
// Source pre-swizzle (lane^4 on odd row-octets) makes the frag gather
// (ds_read_b32 per element) 2-way bank-aliased = free.
// acc[4][8]=128 AGPR; no staging regs -> no spill at the 256-reg cap.
// ---------------------------------------------------------------------------
__global__ __launch_bounds__(512, 2)
void k_gram(const float* __restrict__ q, const float* __restrict__ k,
            unsigned short* __restrict__ Gpart, float* __restrict__ Spart, int nchunk)
{
    extern __shared__ __align__(16) float lds[];
    float* lq = lds;                // [2][32][256] f32 = 64 KB
    float* lk = lds + 2 * 32 * 256; // [2][32][256] f32 = 64 KB

    const int t     = threadIdx.x;
    const int bh    = blockIdx.x & 7;
    const int chunk = blockIdx.x >> 3;
    const int b     = bh >> 2, h = bh & 3;
    const int rows  = NTOK / nchunk;    // 512 at nchunk=32
    const int S     = rows >> 5;        // stages of 32 rows
    const int n0c   = chunk * rows;

    const int lane = t & 63, w = t >> 6;
    const int g = lane >> 4, li = lane & 15;   // n-group, frag row
    const int de0 = (w >> 1) * 64;
    const int e0  = (w & 1) * 128;

    const float* qbase = q + ((size_t)b * NTOK + n0c) * CDIM + h * DHEAD;
    const float* kbase = k + ((size_t)b * NTOK + n0c) * CDIM + h * DHEAD;

    // per-lane source float-offsets for the two row-octet parities
    const int src_off0 = lane << 2;          // 16B chunk = lane
    const int src_off1 = (lane ^ 4) << 2;    // chunk bit2 flipped

    // Each wave stages 4 q-rows + 4 k-rows per stage (8 global_load_lds).
#define STAGE(sidx, buf) do {                                                        \
        _Pragma("unroll") for (int i_ = 0; i_ < 4; ++i_) {                            \
            const int row_ = w * 4 + i_;                                              \
            const int so_  = ((row_ >> 3) & 1) ? src_off1 : src_off0;                 \
            const size_t go_ = (size_t)((sidx) * 32 + row_) * CDIM + so_;             \
            __builtin_amdgcn_global_load_lds(                                         \
                (const __attribute__((address_space(1))) unsigned int*)(qbase + go_), \
                (__attribute__((address_space(3))) unsigned int*)(lq + (buf) * 8192 + row_ * 256), \
                16, 0, 0);                                                            \
            __builtin_amdgcn_global_load_lds(                                         \
                (const __attribute__((address_space(1))) unsigned int*)(kbase + go_), \
                (__attribute__((address_space(3))) unsigned int*)(lk + (buf) * 8192 + row_ * 256), \
                16, 0, 0);                                                            \
        } } while (0)

    // per-frag gather column offsets (floats within a row), swizzle-corrected
    const int swzg = (g & 1) << 2;
    int aoff[4], boff[8];
#pragma unroll
    for (int r = 0; r < 4; ++r) {
        const int ch = de0 + r * 16 + li;
        aoff[r] = ((((ch >> 2) ^ swzg) << 2) | (ch & 3));
    }
#pragma unroll
    for (int c = 0; c < 8; ++c) {
        const int e = e0 + c * 16 + li;
        boff[c] = ((((e >> 2) ^ swzg) << 2) | (e & 3));
    }
    const int rowf = g * 8 * 256;   // float index of my n-group's first row

    STAGE(0, 0);

    float sq[4] = {0.f, 0.f, 0.f, 0.f};
    float sk[8] = {0.f, 0.f, 0.f, 0.f, 0.f, 0.f, 0.f, 0.f};
    f32x4 acc[4][8];
#pragma unroll
    for (int r = 0; r < 4; ++r)
#pragma unroll
        for (int c = 0; c < 8; ++c) acc[r][c] = (f32x4){0.f, 0.f, 0.f, 0.f};

    for (int s = 0; s < S; ++s) {
        const int cur = s & 1;
        if (s + 1 < S) {
            STAGE(s + 1, cur ^ 1);
            asm volatile("s_waitcnt vmcnt(8)" ::: "memory");   // stage-s landed, s+1 in flight
        } else {
            asm volatile("s_waitcnt vmcnt(0)" ::: "memory");
        }
        __builtin_amdgcn_s_barrier();

        const float* bq = lq + cur * 8192 + rowf;
        const float* bk = lk + cur * 8192 + rowf;
        s16x8 af[4], bfr[8];
#pragma unroll
        for (int r = 0; r < 4; ++r) {
            u16x8 p;
            float ssum = 0.f;
#pragma unroll
            for (int j = 0; j < 8; ++j) {
                const float x = bq[j * 256 + aoff[r]];
                ssum += x;
                p[j] = f2bf(x);
            }
            if ((w & 1) == 0) sq[r] += ssum;   // dedupe: e0-pair waves read same A
            af[r] = __builtin_bit_cast(s16x8, p);
        }
#pragma unroll
        for (int c = 0; c < 8; ++c) {
            u16x8 p;
            float ssum = 0.f;
#pragma unroll
            for (int j = 0; j < 8; ++j) {
                const float x = bk[j * 256 + boff[c]];
                ssum += x;
                p[j] = f2bf(x);
            }
            if (w < 2) sk[c] += ssum;          // dedupe: de0-group waves read same B
            bfr[c] = __builtin_bit_cast(s16x8, p);
        }
#pragma unroll
        for (int r = 0; r < 4; ++r)
#pragma unroll
            for (int c = 0; c < 8; ++c)
                acc[r][c] = __builtin_amdgcn_mfma_f32_16x16x32_bf16(af[r], bfr[c], acc[r][c], 0, 0, 0);

        lgkm_barrier();   // my frag reads done -> buffer safe to overwrite
    }
#undef STAGE

    // ---- channel sums: combine the 4 n-groups, then store from lanes 0-15 ----
#pragma unroll
    for (int off = 16; off < 64; off <<= 1) {
#pragma unroll
        for (int r = 0; r < 4; ++r) sq[r] += __shfl_xor(sq[r], off);
#pragma unroll
        for (int c = 0; c < 8; ++c) sk[c] += __shfl_xor(sk[c], off);
    }
    float* sp = Spart + (size_t)(bh * nchunk + chunk) * 512;
    if (((w & 1) == 0) && g == 0) {
#pragma unroll
        for (int r = 0; r < 4; ++r) sp[de0 + r * 16 + li] = sq[r];
    }
    if (w < 2 && g == 0) {
#pragma unroll
        for (int c = 0; c < 8; ++c) sp[256 + e0 + c * 16 + li] = sk[c];
    }

    // ---- Gpart (fp16) via LDS transpose: 4 quarters of 64 de-rows ----
    unsigned short* ls = (unsigned short*)lds;
    unsigned short* gp = Gpart + (size_t)(bh * nchunk + chunk) * 65536;
#pragma unroll
    for (int qtr = 0; qtr < 4; ++qtr) {
        if ((w >> 1) == qtr) {
#pragma unroll
            for (int r = 0; r < 4; ++r) {
                const int de_l = r * 16 + g * 4;
#pragma unroll
                for (int c = 0; c < 8; ++c) {
                    const int e = e0 + c * 16 + li;
#pragma unroll
                    for (int reg = 0; reg < 4; ++reg)
                        ls[(de_l + reg) * 256 + e] = f2h(acc[r][c][reg]);
                }
            }
        }
        lgkm_barrier();
#pragma unroll
        for (int i = 0; i < 4; ++i) {
            const int idx = i * 512 + t;
            *reinterpret_cast<u16x8*>(gp + qtr * 16384 + idx * 8) =
                *reinterpret_cast<const u16x8*>(&ls[idx * 8]);
        }
        lgkm_barrier();
    }
}

// ---------------------------------------------------------------------------
// Kernel 2: fused chunk-reduce + scores + softmax (both branches) + W/beta.
// ---------------------------------------------------------------------------
__global__ __launch_bounds__(256)
void k_scores(const unsigned short* __restrict__ Gpart, const float* __restrict__ Spart,
              const float* __restrict__ wqg, const float* __restrict__ bqg,
              const float* __restrict__ wkg, const float* __restrict__ bkg,
              const float* __restrict__ wvg, const float* __restrict__ bvg,
              const float* __restrict__ wql, const float* __restrict__ bql,
              const float* __restrict__ wkl, const float* __restrict__ bkl,
              const float* __restrict__ wvl, const float* __restrict__ bvl,
              const float* __restrict__ wp,  const float* __restrict__ bp,
              unsigned short* __restrict__ Wm, float* __restrict__ beta, int nchunk)
{
    __shared__ float sSq[256], sSk[256];
    const int t  = threadIdx.x;
    const int bh = blockIdx.x >> 5;
    const int rg = blockIdx.x & 31;
    const int h  = bh & 3;

    float aq = 0.f, ak = 0.f;
    for (int c = 0; c < nchunk; ++c) {
        const float* sp = Spart + (size_t)(bh * nchunk + c) * 512;
        aq += sp[t]; ak += sp[256 + t];
    }
    sSq[t] = aq; sSk[t] = ak;
    __syncthreads();

    const int dl  = t >> 5;
    const int de  = rg * 8 + dl;
    const int e8  = (t & 31) * 8;
    const int cd  = h * DHEAD + de;
    const int ce0 = h * DHEAD + e8;

    float g[8] = {0.f, 0.f, 0.f, 0.f, 0.f, 0.f, 0.f, 0.f};
    const unsigned short* gpb = Gpart + (size_t)bh * nchunk * 65536 + (size_t)de * 256 + e8;
    for (int c = 0; c < nchunk; ++c) {
        h16x8 v = *reinterpret_cast<const h16x8*>(gpb + (size_t)c * 65536);
#pragma unroll
        for (int j = 0; j < 8; ++j) g[j] += (float)v[j];
    }

    const float sqv = sSq[de];
    float skv[8];
#pragma unroll
    for (int j = 0; j < 8; ++j) skv[j] = sSk[e8 + j];

    float wrow[8] = {0.f, 0.f, 0.f, 0.f, 0.f, 0.f, 0.f, 0.f};
    float bacc = 0.f;
    const float scale = 0.03125f;
#pragma unroll
    for (int br = 0; br < 2; ++br) {
        const float* wq = br ? wql : wqg;  const float* bq = br ? bql : bqg;
        const float* wk = br ? wkl : wkg;  const float* bk = br ? bkl : bkg;
        const float* wv = br ? wvl : wvg;  const float* bv = br ? bvl : bvg;
        const float wqv = wq[cd], bqv = bq[cd];

        float s[8], m = -1e30f;
#pragma unroll
        for (int j = 0; j < 8; ++j) {
            const float wkv = wk[ce0 + j], bkv = bk[ce0 + j];
            s[j] = scale * (wqv * wkv * g[j] + wqv * bkv * sqv
                            + bqv * wkv * skv[j] + bqv * bkv * 16384.0f);
            m = fmaxf(m, s[j]);
        }
#pragma unroll
        for (int off = 16; off; off >>= 1) m = fmaxf(m, __shfl_xor(m, off));
        float p[8], sum = 0.f;
#pragma unroll
        for (int j = 0; j < 8; ++j) { p[j] = __expf(s[j] - m); sum += p[j]; }
#pragma unroll
        for (int off = 16; off; off >>= 1) sum += __shfl_xor(sum, off);
        const float inv = 1.f / sum;
#pragma unroll
        for (int j = 0; j < 8; ++j) {
            const float a = p[j] * inv;
            wrow[j] += a * wv[ce0 + j];
            bacc    += a * bv[ce0 + j];
        }
    }
    const float wp2 = 2.f * wp[cd];
    u16x8 pw;
#pragma unroll
    for (int j = 0; j < 8; ++j) pw[j] = f2bf(wp2 * wrow[j]);
    *reinterpret_cast<u16x8*>(Wm + (size_t)bh * 65536 + (size_t)de * 256 + e8) = pw;
#pragma unroll
    for (int off = 16; off; off >>= 1) bacc += __shfl_xor(bacc, off);
    if ((t & 31) == 0) beta[bh * 256 + de] = wp2 * bacc + bp[cd];
}

// ---------------------------------------------------------------------------
// Kernel 3: Out[n][dd] = sum_e W[dd][e]*v[n][ce] + beta[dd].
// 256 thr / 4 waves, 64-row tiles, launch_bounds(256,4) -> 4 independent
// blocks/CU (16 waves): one block's stage-drain overlaps others' compute.
// Regs: 64 arch + 64 AGPR = 128 = exactly the 4-wave/SIMD cap (no spill,
// proven by R6's VGPR_Count=64).
// ---------------------------------------------------------------------------
__global__ __launch_bounds__(256, 4)
void k_out(const float* __restrict__ v, const unsigned short* __restrict__ Wm,
           const float* __restrict__ beta, float* __restrict__ out)
{
    __shared__ __align__(16) unsigned short lv[64 * 256];   // 32 KB
    const int t    = threadIdx.x;
    const int bh   = blockIdx.x & 7;
    const int tile = blockIdx.x >> 3;
    const int b    = bh >> 2, h = bh & 3;
    const int n0   = tile * 64;

#pragma unroll
    for (int i = 0; i < 8; ++i) {
        const int sf = i * 256 + t;
        const int n  = sf >> 5, s = sf & 31;
        const float* vp = v + ((size_t)b * NTOK + n0 + n) * CDIM + (size_t)h * DHEAD + s * 8;
        const float4 v0 = *reinterpret_cast<const float4*>(vp);
        const float4 v1 = *reinterpret_cast<const float4*>(vp + 4);
        const int idx = n * 256 + ((s ^ (n & 7)) * 8);
        *reinterpret_cast<ushort4*>(&lv[idx])     = make_ushort4(f2bf(v0.x), f2bf(v0.y), f2bf(v0.z), f2bf(v0.w));
        *reinterpret_cast<ushort4*>(&lv[idx + 4]) = make_ushort4(f2bf(v1.x), f2bf(v1.y), f2bf(v1.z), f2bf(v1.w));
    }
    __syncthreads();

    const int w = t >> 6, lane = t & 63;
    const int nw  = (w >> 1) * 32;     // 2 n-groups of 32
    const int dd0 = (w & 1) * 128;     // 2 dd-groups of 128
    const unsigned short* Wg = Wm + (size_t)bh * 65536;

    f32x4 acc[2][8];
#pragma unroll
    for (int r = 0; r < 2; ++r)
#pragma unroll
        for (int c = 0; c < 8; ++c) acc[r][c] = (f32x4){0.f, 0.f, 0.f, 0.f};

#pragma unroll
    for (int ks = 0; ks < 8; ++ks) {
        const int e0 = ks * 32;
        s16x8 af[2], bfr[8];
#pragma unroll
        for (int r = 0; r < 2; ++r) {
            const int n  = nw + r * 16 + (lane & 15);
            const int sg = (e0 >> 3) + (lane >> 4);
            af[r] = *reinterpret_cast<const s16x8*>(&lv[n * 256 + ((sg ^ (n & 7)) * 8)]);
        }
#pragma unroll
        for (int c = 0; c < 8; ++c) {
            const int dd = dd0 + c * 16 + (lane & 15);
            const int e  = e0 + (lane >> 4) * 8;
            bfr[c] = *reinterpret_cast<const s16x8*>(Wg + (size_t)dd * 256 + e);
        }
#pragma unroll
        for (int r = 0; r < 2; ++r)
#pragma unroll
            for (int c = 0; c < 8; ++c)
                acc[r][c] = __builtin_amdgcn_mfma_f32_16x16x32_bf16(af[r], bfr[c], acc[r][c], 0, 0, 0);
    }

    float betar[8];
#pragma unroll
    for (int c = 0; c < 8; ++c) betar[c] = beta[bh * 256 + dd0 + c * 16 + (lane & 15)];

#pragma unroll
    for (int r = 0; r < 2; ++r)
#pragma unroll
        for (int c = 0; c < 8; ++c) {
            const int dd = dd0 + c * 16 + (lane & 15);
#pragma unroll
            for (int reg = 0; reg < 4; ++reg) {
                const int n = nw + r * 16 + (lane >> 4) * 4 + reg;
                out[((size_t)b * NTOK + n0 + n) * CDIM + (size_t)h * DHEAD + dd] =
                    acc[r][c][reg] + betar[c];
            }
        }
}

// ---------------------------------------------------------------------------
extern "C" void kernel_launch(void* const* d_in, const int* in_sizes, int n_in,
                              void* d_out, int out_size, void* d_ws, size_t ws_size,
                              hipStream_t stream)
{
    const float* q = (const float*)d_in[0];
    const float* k = (const float*)d_in[1];
    const float* v = (const float*)d_in[2];
    const float* wgt[14];
    for (int i = 0; i < 14; ++i) wgt[i] = (const float*)d_in[3 + i];
    float* out = (float*)d_out;

    int nchunk = 32;
    while (nchunk > 1) {
        size_t need = (size_t)8 * nchunk * 65536 * 2   // Gpart fp16
                    + (size_t)8 * nchunk * 512 * 4     // Spart
                    + (size_t)8 * 65536 * 2            // W bf16
                    + (size_t)8 * 256 * 4 + 1024;      // beta + slack
        if (need <= ws_size) break;
        nchunk >>= 1;
    }

    char* p = (char*)d_ws;
    unsigned short* Gpart = (unsigned short*)p; p += (size_t)8 * nchunk * 65536 * 2;
    float* Spart = (float*)p;                   p += (size_t)8 * nchunk * 512 * 4;
    unsigned short* Wm = (unsigned short*)p;    p += (size_t)8 * 65536 * 2;
    float* beta  = (float*)p;

    k_gram<<<dim3(8 * nchunk), dim3(512), 131072, stream>>>(q, k, Gpart, Spart, nchunk);
    k_scores<<<dim3(8 * 32), dim3(256), 0, stream>>>(
        Gpart, Spart,
        wgt[0], wgt[1], wgt[2], wgt[3], wgt[4], wgt[5],
        wgt[6], wgt[7], wgt[8], wgt[9], wgt[10], wgt[11],
        wgt[12], wgt[13], Wm, beta, nchunk);
    k_out<<<dim3(8 * 256), dim3(256), 0, stream>>>(v, Wm, beta, out);
}

// Round 8
// 180.179 us; speedup vs baseline: 1.1795x; 1.1795x over previous
//
#include <hip/hip_runtime.h>
#include <stdint.h>

#define NTOK 16384
#define CDIM 1024
#define DHEAD 256

typedef short s16x8 __attribute__((ext_vector_type(8)));
typedef unsigned short u16x8 __attribute__((ext_vector_type(8)));
typedef _Float16 h16x8 __attribute__((ext_vector_type(8)));
typedef float f32x4 __attribute__((ext_vector_type(4)));
typedef float f32x16 __attribute__((ext_vector_type(16)));

static __device__ __forceinline__ unsigned short f2bf(float f) {
    union { float f; unsigned u; } x; x.f = f;
    unsigned r = (x.u + 0x7fffu + ((x.u >> 16) & 1u)) >> 16;
    return (unsigned short)r;
}
static __device__ __forceinline__ unsigned short f2h(float f) {
    _Float16 h = (_Float16)f;
    return __builtin_bit_cast(unsigned short, h);
}
// Barrier ordering LDS only — global loads stay in flight across it (T4).
static __device__ __forceinline__ void lgkm_barrier() {
    asm volatile("s_waitcnt lgkmcnt(0)" ::: "memory");
    __builtin_amdgcn_s_barrier();
}

// ---------------------------------------------------------------------------
// Kernel 1: partial Gram G[de][e] over an n-chunk + per-channel sums.
// Tile 256(de) x 128(e): e-split over 2 blocks -> grid 8*nchunk*2 = 512 blocks
// = 2 blocks/CU (the R1-R7 versions all ran 1 block/CU; cross-block overlap
// is the latency-hiding mechanism, m114). Budget per wave: acc 64 AGPR
// (32x32x16 MFMA, 2x2 frags) + ~60 arch < 128 -> launch_bounds(512,4).
// Stage 32 rows: q 32x256, k 32x128 f32 -> bf16 LDS [ch][32n] (24 KB, single
// buffer, two lgkm-only barriers; s+1 loads ride across both).
// ---------------------------------------------------------------------------
__global__ __launch_bounds__(512, 4)
void k_gram(const float* __restrict__ q, const float* __restrict__ k,
            unsigned short* __restrict__ Gpart, float* __restrict__ Spart, int nchunk)
{
    __shared__ __align__(16) unsigned short ls[(256 + 128) * 32];   // 24 KB
    unsigned short* lq = ls;            // [256ch][32n]
    unsigned short* lk = ls + 256 * 32; // [128ch][32n]

    const int t      = threadIdx.x;
    const int eh     = blockIdx.x & 1;
    const int pairid = blockIdx.x >> 1;
    const int bh     = pairid / nchunk;
    const int chunk  = pairid - bh * nchunk;
    const int b      = bh >> 2, h = bh & 3;
    const int rows   = NTOK / nchunk;    // 512 at nchunk=32
    const int S      = rows >> 5;        // stages of 32 rows
    const int n0c    = chunk * rows;

    const int lane = t & 63, w = t >> 6;
    const int wr = w >> 1;               // de-group *64 (0..3)
    const int wc = w & 1;                // e-group *64 within the 128 half
    const int l31 = lane & 31, g2 = lane >> 5;

    // staging roles (all 512 threads)
    const int qcq = t >> 3, qrg = t & 7;     // q: ch-quad 0..63, row-group(4) 0..7
    const int kcq = t >> 4, krs = t & 15;    // k: ch-quad 0..31, row-pair   0..15

    const float* qp = q + ((size_t)b * NTOK + n0c + qrg * 4) * CDIM + h * DHEAD + qcq * 4;
    const float* kp = k + ((size_t)b * NTOK + n0c + krs * 2) * CDIM + h * DHEAD + eh * 128 + kcq * 4;

    f32x4 qv[4], kv[2];
#define QLOAD(sidx) do { const size_t o_ = (size_t)(sidx) * 32 * CDIM;            \
        qv[0] = *reinterpret_cast<const f32x4*>(qp + o_);                          \
        qv[1] = *reinterpret_cast<const f32x4*>(qp + o_ + CDIM);                   \
        qv[2] = *reinterpret_cast<const f32x4*>(qp + o_ + 2 * CDIM);               \
        qv[3] = *reinterpret_cast<const f32x4*>(qp + o_ + 3 * CDIM); } while (0)
#define KLOAD(sidx) do { const size_t o_ = (size_t)(sidx) * 32 * CDIM;            \
        kv[0] = *reinterpret_cast<const f32x4*>(kp + o_);                          \
        kv[1] = *reinterpret_cast<const f32x4*>(kp + o_ + CDIM); } while (0)

    QLOAD(0);
    KLOAD(0);

    float sq[4] = {0.f, 0.f, 0.f, 0.f}, sk[4] = {0.f, 0.f, 0.f, 0.f};
    f32x16 acc[2][2];
#pragma unroll
    for (int r = 0; r < 2; ++r)
#pragma unroll
        for (int c = 0; c < 2; ++c)
#pragma unroll
            for (int j = 0; j < 16; ++j) acc[r][c][j] = 0.f;

    for (int s = 0; s < S; ++s) {
        // ---- consume q regs -> LDS (swizzle slot^(cq&3)), issue q(s+1) ----
#pragma unroll
        for (int j = 0; j < 4; ++j) {
            const int ch = qcq * 4 + j;
            ushort4 p;
            p.x = f2bf(qv[0][j]); p.y = f2bf(qv[1][j]);
            p.z = f2bf(qv[2][j]); p.w = f2bf(qv[3][j]);
            sq[j] += (qv[0][j] + qv[1][j]) + (qv[2][j] + qv[3][j]);
            *reinterpret_cast<ushort4*>(
                &lq[ch * 32 + (((qrg >> 1) ^ (qcq & 3)) * 8) + (qrg & 1) * 4]) = p;
        }
        if (s + 1 < S) QLOAD(s + 1);

        // ---- consume k regs -> LDS, issue k(s+1) ----
#pragma unroll
        for (int j = 0; j < 4; ++j) {
            const int ch = kcq * 4 + j;
            const unsigned pk = (unsigned)f2bf(kv[0][j]) | ((unsigned)f2bf(kv[1][j]) << 16);
            sk[j] += kv[0][j] + kv[1][j];
            *reinterpret_cast<unsigned*>(
                &lk[ch * 32 + (((krs >> 2) ^ (kcq & 3)) * 8) + (krs & 3) * 2]) = pk;
        }
        if (s + 1 < S) KLOAD(s + 1);

        lgkm_barrier();

        // ---- MFMA: 2 k-steps of K=16 over the 32 staged rows ----
#pragma unroll
        for (int kk = 0; kk < 2; ++kk) {
            s16x8 af[2];
#pragma unroll
            for (int r = 0; r < 2; ++r) {
                const int ch   = wr * 64 + r * 32 + l31;
                const int slot = (kk * 2 + g2) ^ ((ch >> 2) & 3);
                af[r] = *reinterpret_cast<const s16x8*>(&lq[ch * 32 + slot * 8]);
            }
#pragma unroll
            for (int c = 0; c < 2; ++c) {
                const int ch   = wc * 64 + c * 32 + l31;
                const int slot = (kk * 2 + g2) ^ ((ch >> 2) & 3);
                const s16x8 bf = *reinterpret_cast<const s16x8*>(&lk[ch * 32 + slot * 8]);
#pragma unroll
                for (int r = 0; r < 2; ++r)
                    acc[r][c] = __builtin_amdgcn_mfma_f32_32x32x16_bf16(af[r], bf, acc[r][c], 0, 0, 0);
            }
        }
        lgkm_barrier();
    }
#undef QLOAD
#undef KLOAD

    // ---- channel sums (q: reduce over qrg=t&7; k: over krs=t&15) ----
#pragma unroll
    for (int off = 1; off < 8; off <<= 1)
#pragma unroll
        for (int j = 0; j < 4; ++j) sq[j] += __shfl_xor(sq[j], off);
#pragma unroll
    for (int off = 1; off < 16; off <<= 1)
#pragma unroll
        for (int j = 0; j < 4; ++j) sk[j] += __shfl_xor(sk[j], off);
    float* sp = Spart + (size_t)(bh * nchunk + chunk) * 512;
    if ((t & 7) == 0)
        *reinterpret_cast<float4*>(&sp[qcq * 4]) = make_float4(sq[0], sq[1], sq[2], sq[3]);
    if ((t & 15) == 0)
        *reinterpret_cast<float4*>(&sp[256 + eh * 128 + kcq * 4]) = make_float4(sk[0], sk[1], sk[2], sk[3]);

    // ---- Gpart (fp16) via LDS transpose: 4 quarters of 64 de-rows x 128 e ----
    unsigned short* gp = Gpart + (size_t)(bh * nchunk + chunk) * 65536;
#pragma unroll
    for (int qtr = 0; qtr < 4; ++qtr) {
        if (wr == qtr) {
#pragma unroll
            for (int r = 0; r < 2; ++r)
#pragma unroll
                for (int c = 0; c < 2; ++c)
#pragma unroll
                    for (int reg = 0; reg < 16; ++reg) {
                        const int de_l = r * 32 + (reg & 3) + 8 * (reg >> 2) + 4 * g2;
                        const int e_l  = wc * 64 + c * 32 + l31;
                        ls[de_l * 128 + e_l] = f2h(acc[r][c][reg]);
                    }
        }
        lgkm_barrier();
        {
            const int de_r = t >> 3, col = (t & 7) * 16;
            unsigned short* dst = gp + (qtr * 64 + de_r) * 256 + eh * 128 + col;
            *reinterpret_cast<u16x8*>(dst)     = *reinterpret_cast<const u16x8*>(&ls[de_r * 128 + col]);
            *reinterpret_cast<u16x8*>(dst + 8) = *reinterpret_cast<const u16x8*>(&ls[de_r * 128 + col + 8]);
        }
        lgkm_barrier();
    }
}

// ---------------------------------------------------------------------------
// Kernel 2: fused chunk-reduce + scores + softmax (both branches) + W/beta.
// W written in k_out's fragment order: Wf[bh][ks=e/32][dd][e%32] bf16 so k_out
// B-frag loads are 1KB coalesced wave reads.
// ---------------------------------------------------------------------------
__global__ __launch_bounds__(256)
void k_scores(const unsigned short* __restrict__ Gpart, const float* __restrict__ Spart,
              const float* __restrict__ wqg, const float* __restrict__ bqg,
              const float* __restrict__ wkg, const float* __restrict__ bkg,
              const float* __restrict__ wvg, const float* __restrict__ bvg,
              const float* __restrict__ wql, const float* __restrict__ bql,
              const float* __restrict__ wkl, const float* __restrict__ bkl,
              const float* __restrict__ wvl, const float* __restrict__ bvl,
              const float* __restrict__ wp,  const float* __restrict__ bp,
              unsigned short* __restrict__ Wf, float* __restrict__ beta, int nchunk)
{
    __shared__ float sSq[256], sSk[256];
    const int t  = threadIdx.x;
    const int bh = blockIdx.x >> 5;
    const int rg = blockIdx.x & 31;
    const int h  = bh & 3;

    float aq = 0.f, ak = 0.f;
    for (int c = 0; c < nchunk; ++c) {
        const float* sp = Spart + (size_t)(bh * nchunk + c) * 512;
        aq += sp[t]; ak += sp[256 + t];
    }
    sSq[t] = aq; sSk[t] = ak;
    __syncthreads();

    const int dl  = t >> 5;
    const int de  = rg * 8 + dl;
    const int e8  = (t & 31) * 8;
    const int cd  = h * DHEAD + de;
    const int ce0 = h * DHEAD + e8;

    float g[8] = {0.f, 0.f, 0.f, 0.f, 0.f, 0.f, 0.f, 0.f};
    const unsigned short* gpb = Gpart + (size_t)bh * nchunk * 65536 + (size_t)de * 256 + e8;
    for (int c = 0; c < nchunk; ++c) {
        h16x8 v = *reinterpret_cast<const h16x8*>(gpb + (size_t)c * 65536);
#pragma unroll
        for (int j = 0; j < 8; ++j) g[j] += (float)v[j];
    }

    const float sqv = sSq[de];
    float skv[8];
#pragma unroll
    for (int j = 0; j < 8; ++j) skv[j] = sSk[e8 + j];

    float wrow[8] = {0.f, 0.f, 0.f, 0.f, 0.f, 0.f, 0.f, 0.f};
    float bacc = 0.f;
    const float scale = 0.03125f;
#pragma unroll
    for (int br = 0; br < 2; ++br) {
        const float* wq = br ? wql : wqg;  const float* bq = br ? bql : bqg;
        const float* wk = br ? wkl : wkg;  const float* bk = br ? bkl : bkg;
        const float* wv = br ? wvl : wvg;  const float* bv = br ? bvl : bvg;
        const float wqv = wq[cd], bqv = bq[cd];

        float s[8], m = -1e30f;
#pragma unroll
        for (int j = 0; j < 8; ++j) {
            const float wkv = wk[ce0 + j], bkv = bk[ce0 + j];
            s[j] = scale * (wqv * wkv * g[j] + wqv * bkv * sqv
                            + bqv * wkv * skv[j] + bqv * bkv * 16384.0f);
            m = fmaxf(m, s[j]);
        }
#pragma unroll
        for (int off = 16; off; off >>= 1) m = fmaxf(m, __shfl_xor(m, off));
        float p[8], sum = 0.f;
#pragma unroll
        for (int j = 0; j < 8; ++j) { p[j] = __expf(s[j] - m); sum += p[j]; }
#pragma unroll
        for (int off = 16; off; off >>= 1) sum += __shfl_xor(sum, off);
        const float inv = 1.f / sum;
#pragma unroll
        for (int j = 0; j < 8; ++j) {
            const float a = p[j] * inv;
            wrow[j] += a * wv[ce0 + j];
            bacc    += a * bv[ce0 + j];
        }
    }
    const float wp2 = 2.f * wp[cd];
    u16x8 pw;
#pragma unroll
    for (int j = 0; j < 8; ++j) pw[j] = f2bf(wp2 * wrow[j]);
    const int ks = e8 >> 5, ew = e8 & 31;
    *reinterpret_cast<u16x8*>(Wf + (size_t)bh * 65536 + ((ks * 256 + de) * 32 + ew)) = pw;
#pragma unroll
    for (int off = 16; off; off >>= 1) bacc += __shfl_xor(bacc, off);
    if ((t & 31) == 0) beta[bh * 256 + de] = wp2 * bacc + bp[cd];
}

// ---------------------------------------------------------------------------
// Kernel 3: Out[n][dd] = sum_e W[dd][e]*v[n][ce] + beta[dd].
// 128-row tiles, 8 waves (32n x 128dd each, acc 64 AGPR), 16-row staging
// sub-phases (16 regs in flight) -> ~115 unified regs, 64KB LDS ->
// 2 blocks/CU via launch_bounds(512,4). W frags coalesced via Wf layout.
// ---------------------------------------------------------------------------
__global__ __launch_bounds__(512, 4)
void k_out(const float* __restrict__ v, const unsigned short* __restrict__ Wf,
           const float* __restrict__ beta, float* __restrict__ out)
{
    __shared__ __align__(16) unsigned short lv[128 * 256];   // 64 KB
    const int t    = threadIdx.x;
    const int bh   = blockIdx.x >> 7;
    const int tile = blockIdx.x & 127;
    const int b    = bh >> 2, h = bh & 3;
    const int n0   = tile * 128;

    const int nr = t >> 5, ch0 = (t & 31) * 8;
    const float* vp = v + ((size_t)b * NTOK + n0 + nr) * CDIM + (size_t)h * DHEAD + ch0;

    f32x4 sA[2], sB[2];
#define VLOAD(dst, i) do { const size_t o_ = (size_t)(i) * 16 * CDIM;              \
        dst[0] = *reinterpret_cast<const f32x4*>(vp + o_);                         \
        dst[1] = *reinterpret_cast<const f32x4*>(vp + o_ + 4); } while (0)

    VLOAD(sA, 0);
    VLOAD(sB, 1);
#pragma unroll
    for (int i = 0; i < 8; i += 2) {
        {
            const int n = i * 16 + nr;
            u16x8 p;
#pragma unroll
            for (int j = 0; j < 4; ++j) { p[j] = f2bf(sA[0][j]); p[4 + j] = f2bf(sA[1][j]); }
            *reinterpret_cast<u16x8*>(&lv[n * 256 + (((t & 31) ^ (n & 7)) * 8)]) = p;
        }
        if (i + 2 < 8) VLOAD(sA, i + 2);
        {
            const int n = (i + 1) * 16 + nr;
            u16x8 p;
#pragma unroll
            for (int j = 0; j < 4; ++j) { p[j] = f2bf(sB[0][j]); p[4 + j] = f2bf(sB[1][j]); }
            *reinterpret_cast<u16x8*>(&lv[n * 256 + (((t & 31) ^ (n & 7)) * 8)]) = p;
        }
        if (i + 3 < 8) VLOAD(sB, i + 3);
    }
#undef VLOAD
    __syncthreads();

    const int w = t >> 6, lane = t & 63, li = lane & 15, g = lane >> 4;
    const int nw  = (w >> 1) * 32;     // 4 n-groups of 32
    const int dd0 = (w & 1) * 128;     // 2 dd-groups of 128
    const unsigned short* wf = Wf + (size_t)bh * 65536;

    f32x4 acc[2][8];
#pragma unroll
    for (int r = 0; r < 2; ++r)
#pragma unroll
        for (int c = 0; c < 8; ++c) acc[r][c] = (f32x4){0.f, 0.f, 0.f, 0.f};

#pragma unroll
    for (int ks = 0; ks < 8; ++ks) {
        s16x8 af[2];
#pragma unroll
        for (int r = 0; r < 2; ++r) {
            const int n = nw + r * 16 + li;
            af[r] = *reinterpret_cast<const s16x8*>(&lv[n * 256 + (((ks * 4 + g) ^ (n & 7)) * 8)]);
        }
#pragma unroll
        for (int c = 0; c < 8; ++c) {
            const int dd = dd0 + c * 16 + li;
            const s16x8 bf = *reinterpret_cast<const s16x8*>(wf + ((ks * 256 + dd) * 32 + g * 8));
            acc[0][c] = __builtin_amdgcn_mfma_f32_16x16x32_bf16(af[0], bf, acc[0][c], 0, 0, 0);
            acc[1][c] = __builtin_amdgcn_mfma_f32_16x16x32_bf16(af[1], bf, acc[1][c], 0, 0, 0);
        }
    }

    float betar[8];
#pragma unroll
    for (int c = 0; c < 8; ++c) betar[c] = beta[bh * 256 + dd0 + c * 16 + li];

#pragma unroll
    for (int r = 0; r < 2; ++r)
#pragma unroll
        for (int c = 0; c < 8; ++c) {
            const int dd = dd0 + c * 16 + li;
#pragma unroll
            for (int reg = 0; reg < 4; ++reg) {
                const int n = nw + r * 16 + g * 4 + reg;
                out[((size_t)b * NTOK + n0 + n) * CDIM + (size_t)h * DHEAD + dd] =
                    acc[r][c][reg] + betar[c];
            }
        }
}

// ---------------------------------------------------------------------------
extern "C" void kernel_launch(void* const* d_in, const int* in_sizes, int n_in,
                              void* d_out, int out_size, void* d_ws, size_t ws_size,
                              hipStream_t stream)
{
    const float* q = (const float*)d_in[0];
    const float* k = (const float*)d_in[1];
    const float* v = (const float*)d_in[2];
    const float* wgt[14];
    for (int i = 0; i < 14; ++i) wgt[i] = (const float*)d_in[3 + i];
    float* out = (float*)d_out;

    int nchunk = 32;
    while (nchunk > 1) {
        size_t need = (size_t)8 * nchunk * 65536 * 2   // Gpart fp16
                    + (size_t)8 * nchunk * 512 * 4     // Spart
                    + (size_t)8 * 65536 * 2            // Wf bf16
                    + (size_t)8 * 256 * 4 + 1024;      // beta + slack
        if (need <= ws_size) break;
        nchunk >>= 1;
    }

    char* p = (char*)d_ws;
    unsigned short* Gpart = (unsigned short*)p; p += (size_t)8 * nchunk * 65536 * 2;
    float* Spart = (float*)p;                   p += (size_t)8 * nchunk * 512 * 4;
    unsigned short* Wf = (unsigned short*)p;    p += (size_t)8 * 65536 * 2;
    float* beta  = (float*)p;

    k_gram<<<dim3(8 * nchunk * 2), dim3(512), 0, stream>>>(q, k, Gpart, Spart, nchunk);
    k_scores<<<dim3(8 * 32), dim3(256), 0, stream>>>(
        Gpart, Spart,
        wgt[0], wgt[1], wgt[2], wgt[3], wgt[4], wgt[5],
        wgt[6], wgt[7], wgt[8], wgt[9], wgt[10], wgt[11],
        wgt[12], wgt[13], Wf, beta, nchunk);
    k_out<<<dim3(8 * 128), dim3(512), 0, stream>>>(v, Wf, beta, out);
}